// Round 1
// baseline (572.583 us; speedup 1.0000x reference)
//
#include <hip/hip_runtime.h>

// DCN layer, fused:
//   s[i]     = sum_j x_l[i,j] * w[j]
//   out[i,j] = x_0[i,j] * s[i] + b[j] + x_l[i,j]
// Shapes: x_l, x_0: [B=65536, DIM=1024] fp32; w, b: [1024] fp32; out: [B, DIM] fp32.
//
// Structure: one WAVE per row (64 lanes x 16 floats), 4 rows per 256-thread block.
//  - No LDS, no __syncthreads: the previous version's barrier blocked the compiler
//    from overlapping the x_0 load with the x_l reduce, exposing 2 full HBM
//    latencies with only 16 B/thread in flight (measured 3.0 TB/s, latency-bound).
//  - All 8 float4 loads (128 B/thread) are issued before any dependent use:
//    in-flight bytes per CU >> the ~22 KB needed to hide ~900-cycle HBM latency.
//  - Chunked column layout: chunk k -> cols [k*256 + lane*4), so every load/store
//    instruction is a fully-coalesced contiguous 1 KiB per wave.

#define DIM 1024
#define BLOCK 256          // 4 waves = 4 rows per block

__global__ __launch_bounds__(BLOCK) void dcn_fused_kernel(
    const float* __restrict__ x_l,
    const float* __restrict__ x_0,
    const float* __restrict__ w,
    const float* __restrict__ b,
    float* __restrict__ out)
{
    const int wave = threadIdx.x >> 6;          // 0..3
    const int lane = threadIdx.x & 63;          // 0..63
    const int row  = blockIdx.x * 4 + wave;
    const size_t rowbase = (size_t)row * DIM;
    const int c0 = lane * 4;                    // column of this lane's float4 in chunk 0

    // Issue ALL global loads up front — 8x16B of row data in flight per thread,
    // plus the (L1/L2-resident) w and b vectors.
    float4 xl[4], x0[4], wv[4], bv[4];
    #pragma unroll
    for (int k = 0; k < 4; ++k)
        xl[k] = *(const float4*)(x_l + rowbase + k * 256 + c0);
    #pragma unroll
    for (int k = 0; k < 4; ++k)
        x0[k] = *(const float4*)(x_0 + rowbase + k * 256 + c0);
    #pragma unroll
    for (int k = 0; k < 4; ++k)
        wv[k] = *(const float4*)(w + k * 256 + c0);
    #pragma unroll
    for (int k = 0; k < 4; ++k)
        bv[k] = *(const float4*)(b + k * 256 + c0);

    // Per-lane partial dot product over 16 elements.
    float partial = 0.0f;
    #pragma unroll
    for (int k = 0; k < 4; ++k) {
        partial = fmaf(xl[k].x, wv[k].x, partial);
        partial = fmaf(xl[k].y, wv[k].y, partial);
        partial = fmaf(xl[k].z, wv[k].z, partial);
        partial = fmaf(xl[k].w, wv[k].w, partial);
    }

    // Wave-64 butterfly reduction: every lane ends with the full row sum.
    #pragma unroll
    for (int off = 1; off < 64; off <<= 1)
        partial += __shfl_xor(partial, off, 64);
    const float s = partial;

    // Epilogue: out = x0 * s + (b + xl), fully coalesced float4 stores.
    #pragma unroll
    for (int k = 0; k < 4; ++k) {
        float4 o;
        o.x = fmaf(x0[k].x, s, bv[k].x + xl[k].x);
        o.y = fmaf(x0[k].y, s, bv[k].y + xl[k].y);
        o.z = fmaf(x0[k].z, s, bv[k].z + xl[k].z);
        o.w = fmaf(x0[k].w, s, bv[k].w + xl[k].w);
        *(float4*)(out + rowbase + k * 256 + c0) = o;
    }
}

extern "C" void kernel_launch(void* const* d_in, const int* in_sizes, int n_in,
                              void* d_out, int out_size, void* d_ws, size_t ws_size,
                              hipStream_t stream) {
    const float* x_l = (const float*)d_in[0];
    const float* x_0 = (const float*)d_in[1];
    const float* w   = (const float*)d_in[2];
    const float* b   = (const float*)d_in[3];
    float* out = (float*)d_out;

    const int B = in_sizes[0] / DIM;            // 65536
    dcn_fused_kernel<<<B / 4, BLOCK, 0, stream>>>(x_l, x_0, w, b, out);
}